// Round 7
// baseline (271.765 us; speedup 1.0000x reference)
//
#include <hip/hip_runtime.h>
#include <hip/hip_bf16.h>
#include <stdint.h>

#define NN 4096      // nodes
#define NF 512       // NFEAT = NHEADS*NHID
#define NH 64        // NHID
#define NCLS 40      // NCLASS
#define NHEADS 8
#define LOG2E 1.4426950408889634f

typedef __attribute__((ext_vector_type(8))) short bh8;
typedef __attribute__((ext_vector_type(4))) float f32x4;

__device__ __forceinline__ unsigned short f2bu(float f) {
    union { float f; unsigned u; } v; v.f = f;
    unsigned r = (v.u + 0x7FFFu + ((v.u >> 16) & 1u)) >> 16;
    return (unsigned short)r;
}
__device__ __forceinline__ float lrelu(float x) { return fmaxf(x, 0.2f * x); }
__device__ __forceinline__ float elu1(float x) { return x > 0.f ? x : expm1f(x); }
__device__ __forceinline__ float exp2fast(float x) {
    float r; asm("v_exp_f32 %0, %1" : "=v"(r) : "v"(x)); return r;
}
// ordered-uint encode/decode for float atomicMax
__device__ __forceinline__ unsigned fenc(float f) {
    unsigned u = __builtin_bit_cast(unsigned, f);
    return ((int)u < 0) ? ~u : (u | 0x80000000u);
}
__device__ __forceinline__ float fdec(unsigned k) {
    unsigned u = (k & 0x80000000u) ? (k ^ 0x80000000u) : ~k;
    return __builtin_bit_cast(float, u);
}
// 1-bit sign-extended field extract: 0 or 0xFFFFFFFF
__device__ __forceinline__ int sbfe1(unsigned v, int off) {
#if __has_builtin(__builtin_amdgcn_sbfe)
    return __builtin_amdgcn_sbfe((int)v, off, 1);
#else
    return ((int)(v << (31 - off))) >> 31;
#endif
}
__device__ __forceinline__ float bmask(float p, unsigned mdw, int bit) {
    return __builtin_bit_cast(float,
        __builtin_bit_cast(unsigned, p) & (unsigned)sbfe1(mdw, bit));
}
// pack two f32 -> bf16 pair (RN)
__device__ __forceinline__ unsigned pack2(float x, float y) {
    unsigned ux = __builtin_bit_cast(unsigned, x), uy = __builtin_bit_cast(unsigned, y);
    ux += 0x7FFFu + ((ux >> 16) & 1u);
    uy += 0x7FFFu + ((uy >> 16) & 1u);
    return __builtin_amdgcn_perm(uy, ux, 0x07060302u);
}

// ---------------- fused prep: adj bitplanes (adjq layout) + x/W bf16 + FM init ----------------
// adjq[ib][jt4][row:64][grp:4] dwords; dword bits[8u+e] = adj[ib*64+row][ (jt4*4+u)*32 + grp*8 + e ]
// blocks [0,8192): adj (half-row each); [8192,10240): xb; [10240,11264): WT; [11264,11360): WoT
__global__ __launch_bounds__(256) void prep_all_k(const float* __restrict__ x,
                                                  const float* __restrict__ adj,
                                                  const float* __restrict__ Ws,
                                                  const float* __restrict__ Wo,
                                                  unsigned short* __restrict__ xb,
                                                  unsigned short* __restrict__ WT,
                                                  unsigned short* __restrict__ WoT,
                                                  unsigned* __restrict__ adjq,
                                                  unsigned* __restrict__ FM1u,
                                                  unsigned* __restrict__ FM2u) {
    const int bid = blockIdx.x, tid = threadIdx.x;
    if (bid < 8192) {
        __shared__ unsigned char sm[4][64];
        const int i = bid >> 1, half = bid & 1;
        const float* rp = adj + (size_t)i * NN + half * 2048 + tid * 8;
        float4 v0 = ((const float4*)rp)[0];
        float4 v1 = ((const float4*)rp)[1];
        unsigned b = (v0.x > 0.f ? 1u : 0u) | (v0.y > 0.f ? 2u : 0u) |
                     (v0.z > 0.f ? 4u : 0u) | (v0.w > 0.f ? 8u : 0u) |
                     (v1.x > 0.f ? 16u : 0u) | (v1.y > 0.f ? 32u : 0u) |
                     (v1.z > 0.f ? 64u : 0u) | (v1.w > 0.f ? 128u : 0u);
        sm[tid & 3][tid >> 2] = (unsigned char)b;
        __syncthreads();
        if (tid < 64) {
            int gp = tid >> 4, word = tid & 15;
            unsigned d = *(const unsigned*)&sm[gp][word * 4];
            int ib = i >> 6, row = i & 63, jt4 = half * 16 + word;
            adjq[(size_t)ib * 8192 + (size_t)jt4 * 256 + row * 4 + gp] = d;
        }
    } else if (bid < 10240) {
        if (bid == 8192) {
            if (tid < 8) FM1u[tid] = 0u;
            if (tid == 8) FM2u[0] = 0u;
        }
        int t = (bid - 8192) * 256 + tid;
        float4 v = ((const float4*)x)[t];
        uint2 o; o.x = pack2(v.x, v.y); o.y = pack2(v.z, v.w);
        ((uint2*)xb)[t] = o;
    } else if (bid < 11264) {
        int j = (bid - 10240) * 256 + tid;
        int c = j >> 9, k = j & 511;
        WT[j] = f2bu(Ws[(size_t)(c >> 6) * (NF * NH) + (size_t)k * NH + (c & 63)]);
    } else {
        int j = (bid - 11264) * 256 + tid;
        int c = j >> 9, k = j & 511;
        WoT[j] = f2bu(c < NCLS ? Wo[(size_t)k * NCLS + c] : 0.f);
    }
}

// ---------------- GEMM1 (BM=128, 8 waves): Bp1 = pack(x @ Wcat), f1/f2 + FM1 ----------------
__global__ __launch_bounds__(512) void gemm1_k(const unsigned short* __restrict__ xb,
                                               const unsigned short* __restrict__ WT,
                                               const float* __restrict__ a_s,
                                               unsigned short* __restrict__ Bp1,
                                               float* __restrict__ f1L,
                                               float* __restrict__ f2L,
                                               unsigned* __restrict__ FM1u) {
    __shared__ unsigned short xs[128 * 40];
    __shared__ unsigned short wsm[64 * 40];
    const int tid = threadIdx.x;
    const int w = tid >> 6, lane = tid & 63, r16 = lane & 15, grp = lane >> 4;
    const int i0 = blockIdx.x << 7, h = blockIdx.y, c0 = h << 6;
    const int srow = tid >> 2, sseg = tid & 3;
    const unsigned short* xsrc = xb + (size_t)(i0 + srow) * NF + sseg * 8;
    const unsigned short* wsrc = WT + (size_t)(c0 + (srow & 63)) * NF + sseg * 8;
    f32x4 a0 = {0,0,0,0}, a1 = {0,0,0,0}, a2 = {0,0,0,0}, a3 = {0,0,0,0};
    bh8 rx = *(const bh8*)(xsrc);
    bh8 rw; if (tid < 256) rw = *(const bh8*)(wsrc);
    for (int kb = 0; kb < NF; kb += 32) {
        *(bh8*)(xs + srow * 40 + sseg * 8) = rx;
        if (tid < 256) *(bh8*)(wsm + srow * 40 + sseg * 8) = rw;
        __syncthreads();
        if (kb + 32 < NF) {
            rx = *(const bh8*)(xsrc + kb + 32);
            if (tid < 256) rw = *(const bh8*)(wsrc + kb + 32);
        }
        bh8 af = *(const bh8*)(xs + (w * 16 + r16) * 40 + grp * 8);
        bh8 b0 = *(const bh8*)(wsm + (r16) * 40 + grp * 8);
        bh8 b1 = *(const bh8*)(wsm + (16 + r16) * 40 + grp * 8);
        bh8 b2 = *(const bh8*)(wsm + (32 + r16) * 40 + grp * 8);
        bh8 b3 = *(const bh8*)(wsm + (48 + r16) * 40 + grp * 8);
        a0 = __builtin_amdgcn_mfma_f32_16x16x32_bf16(af, b0, a0, 0, 0, 0);
        a1 = __builtin_amdgcn_mfma_f32_16x16x32_bf16(af, b1, a1, 0, 0, 0);
        a2 = __builtin_amdgcn_mfma_f32_16x16x32_bf16(af, b2, a2, 0, 0, 0);
        a3 = __builtin_amdgcn_mfma_f32_16x16x32_bf16(af, b3, a3, 0, 0, 0);
        __syncthreads();
    }
    // direct B-panel write
    const int jt = (i0 >> 5) + (w >> 1);
    const int kg = ((w & 1) << 1) + (grp >> 1);
    const int lanep = kg * 16 + r16;
    const int ebase = (grp & 1) * 4;
    unsigned short* bp = Bp1 + ((size_t)(h * 128 + jt)) * 2048 + lanep * 8 + ebase;
    {
        uint2 v;
        v.x = pack2(a0[0], a0[1]); v.y = pack2(a0[2], a0[3]); *(uint2*)(bp + 0 * 512) = v;
        v.x = pack2(a1[0], a1[1]); v.y = pack2(a1[2], a1[3]); *(uint2*)(bp + 1 * 512) = v;
        v.x = pack2(a2[0], a2[1]); v.y = pack2(a2[2], a2[3]); *(uint2*)(bp + 2 * 512) = v;
        v.x = pack2(a3[0], a3[1]); v.y = pack2(a3[2], a3[3]); *(uint2*)(bp + 3 * 512) = v;
    }
    const float* ap = a_s + h * 128;
    float a1v[4], a2v[4];
#pragma unroll
    for (int n = 0; n < 4; ++n) { a1v[n] = ap[r16 + 16 * n]; a2v[n] = ap[64 + r16 + 16 * n]; }
    float wmax = -3.0e38f;
#pragma unroll
    for (int r = 0; r < 4; ++r) {
        const int orow = i0 + w * 16 + grp * 4 + r;
        float s1 = a0[r] * a1v[0] + a1[r] * a1v[1] + a2[r] * a1v[2] + a3[r] * a1v[3];
        float s2 = a0[r] * a2v[0] + a1[r] * a2v[1] + a2[r] * a2v[2] + a3[r] * a2v[3];
#pragma unroll
        for (int o2 = 1; o2 < 16; o2 <<= 1) { s1 += __shfl_xor(s1, o2); s2 += __shfl_xor(s2, o2); }
        s1 *= LOG2E; s2 *= LOG2E;
        if (r16 == 0) { f1L[h * NN + orow] = s1; f2L[h * NN + orow] = s2; }
        wmax = fmaxf(wmax, s2);
    }
    wmax = fmaxf(wmax, __shfl_xor(wmax, 16));
    wmax = fmaxf(wmax, __shfl_xor(wmax, 32));
    if (lane == 0) atomicMax(&FM1u[h], fenc(wmax));
}

// ---------------- GEMM2: Bp2 = pack(x2 @ W_out), f12/f22 + FM2 ----------------
__global__ __launch_bounds__(256) void gemm2_k(const unsigned short* __restrict__ x2b,
                                               const unsigned short* __restrict__ WoT,
                                               const float* __restrict__ a_out,
                                               unsigned short* __restrict__ Bp2,
                                               float* __restrict__ f12L,
                                               float* __restrict__ f22L,
                                               unsigned* __restrict__ FM2u) {
    __shared__ unsigned short xs[64 * 40];
    __shared__ unsigned short wsm[48 * 40];
    const int tid = threadIdx.x;
    const int w = tid >> 6, lane = tid & 63, r16 = lane & 15, grp = lane >> 4;
    const int i0 = blockIdx.x << 6;
    const int srow = tid >> 2, sseg = tid & 3;
    const unsigned short* xsrc = x2b + (size_t)(i0 + srow) * NF + sseg * 8;
    const unsigned short* wsrc = WoT + (size_t)srow * NF + sseg * 8;
    f32x4 a0 = {0,0,0,0}, a1 = {0,0,0,0}, a2 = {0,0,0,0};
    bh8 rx = *(const bh8*)(xsrc);
    bh8 rw; if (tid < 192) rw = *(const bh8*)(wsrc);
    for (int kb = 0; kb < NF; kb += 32) {
        *(bh8*)(xs + srow * 40 + sseg * 8) = rx;
        if (tid < 192) *(bh8*)(wsm + srow * 40 + sseg * 8) = rw;
        __syncthreads();
        if (kb + 32 < NF) {
            rx = *(const bh8*)(xsrc + kb + 32);
            if (tid < 192) rw = *(const bh8*)(wsrc + kb + 32);
        }
        bh8 af = *(const bh8*)(xs + (w * 16 + r16) * 40 + grp * 8);
        bh8 b0 = *(const bh8*)(wsm + (r16) * 40 + grp * 8);
        bh8 b1 = *(const bh8*)(wsm + (16 + r16) * 40 + grp * 8);
        bh8 b2 = *(const bh8*)(wsm + (32 + r16) * 40 + grp * 8);
        a0 = __builtin_amdgcn_mfma_f32_16x16x32_bf16(af, b0, a0, 0, 0, 0);
        a1 = __builtin_amdgcn_mfma_f32_16x16x32_bf16(af, b1, a1, 0, 0, 0);
        a2 = __builtin_amdgcn_mfma_f32_16x16x32_bf16(af, b2, a2, 0, 0, 0);
        __syncthreads();
    }
    const int jt = (i0 >> 5) + (w >> 1);
    const int kg = ((w & 1) << 1) + (grp >> 1);
    const int lanep = kg * 16 + r16;
    const int ebase = (grp & 1) * 4;
    unsigned short* bp = Bp2 + (size_t)jt * 1536 + lanep * 8 + ebase;
    {
        uint2 v;
        v.x = pack2(a0[0], a0[1]); v.y = pack2(a0[2], a0[3]); *(uint2*)(bp + 0 * 512) = v;
        v.x = pack2(a1[0], a1[1]); v.y = pack2(a1[2], a1[3]); *(uint2*)(bp + 1 * 512) = v;
        v.x = pack2(a2[0], a2[1]); v.y = pack2(a2[2], a2[3]); *(uint2*)(bp + 2 * 512) = v;
    }
    float a1v[3], a2v[3];
#pragma unroll
    for (int n = 0; n < 3; ++n) {
        int col = r16 + 16 * n;
        a1v[n] = col < NCLS ? a_out[col] : 0.f;
        a2v[n] = col < NCLS ? a_out[NCLS + col] : 0.f;
    }
    float wmax = -3.0e38f;
#pragma unroll
    for (int r = 0; r < 4; ++r) {
        const int orow = i0 + w * 16 + grp * 4 + r;
        float s1 = a0[r] * a1v[0] + a1[r] * a1v[1] + a2[r] * a1v[2];
        float s2 = a0[r] * a2v[0] + a1[r] * a2v[1] + a2[r] * a2v[2];
#pragma unroll
        for (int o2 = 1; o2 < 16; o2 <<= 1) { s1 += __shfl_xor(s1, o2); s2 += __shfl_xor(s2, o2); }
        s1 *= LOG2E; s2 *= LOG2E;
        if (r16 == 0) { f12L[orow] = s1; f22L[orow] = s2; }
        wmax = fmaxf(wmax, s2);
    }
    wmax = fmaxf(wmax, __shfl_xor(wmax, 16));
    wmax = fmaxf(wmax, __shfl_xor(wmax, 32));
    if (lane == 0) atomicMax(&FM2u[0], fenc(wmax));
}

// ---------------- attn layer 1: EF tables in LDS, coalesced adjq loads ----------------
__global__ __launch_bounds__(512, 6) void attn1_k(const unsigned short* __restrict__ Bp1,
                                                  const unsigned* __restrict__ adjq,
                                                  const float* __restrict__ f1L,
                                                  const float* __restrict__ f2L,
                                                  const unsigned* __restrict__ FM1u,
                                                  unsigned short* __restrict__ x2b) {
    __shared__ float EFs[8192];                 // 32 KiB (reused as comb)
    const int tid = threadIdx.x, w = tid >> 6, lane = tid & 63;
    const int r16 = lane & 15, grp = lane >> 4;
    const int rowg = w & 3, jq = w >> 2;
    const int h = blockIdx.y;
    const int i0 = blockIdx.x * 64;
    const float fm = fdec(FM1u[h]);
    const float* f2p = f2L + h * NN;
    for (int t = 0; t < 8; ++t) {
        int j = tid + t * 512;
        float d = f2p[j] - fm;
        EFs[2 * j] = exp2fast(d);
        EFs[2 * j + 1] = exp2fast(0.2f * d);
    }
    const int irow = i0 + rowg * 16 + r16;
    const float f1v = f1L[h * NN + irow];
    const float mL = lrelu(f1v + fm);
    const float A = exp2fast(f1v + fm - mL);
    const float B = exp2fast(__builtin_fmaf(0.2f, f1v + fm, -mL));
    __syncthreads();
    const int jtbase = jq * 64;
    // coalesced adj: adjq[ib][jt4][row][grp], wave covers 16 rows x 4 grp = 256B
    const unsigned* adjl = adjq + (size_t)blockIdx.x * 8192 + (rowg * 16 + r16) * 4 + grp;
    const float* efp = EFs + grp * 16;
    const unsigned short* Bbase = Bp1 + (size_t)h * 128 * 2048 + lane * 8;
    f32x4 acc0 = {0,0,0,0}, acc1 = {0,0,0,0}, acc2 = {0,0,0,0}, acc3 = {0,0,0,0}, accd = {0,0,0,0};
    const short ov = (r16 == 0) ? (short)0x3F80 : (short)0;
    bh8 ones;
#pragma unroll
    for (int e = 0; e < 8; ++e) ones[e] = ov;
    bh8 nb0, nb1, nb2, nb3;
#define PREF1(JT) { const unsigned short* Bn = Bbase + (size_t)(JT) * 2048;              \
        nb0 = *(const bh8*)(Bn);        nb1 = *(const bh8*)(Bn + 512);                    \
        nb2 = *(const bh8*)(Bn + 1024); nb3 = *(const bh8*)(Bn + 1536); }
    PREF1(jtbase);
    unsigned nmdw = adjl[(size_t)(jq * 16) * 256];
    for (int jt4i = 0; jt4i < 16; ++jt4i) {
        const int jt4 = jq * 16 + jt4i;
        const unsigned mdw = nmdw;
        if (jt4i < 15) nmdw = adjl[(size_t)(jt4 + 1) * 256];
#pragma unroll
        for (int u = 0; u < 4; ++u) {
            const int jt = jt4 * 4 + u;
            bh8 b0 = nb0, b1 = nb1, b2 = nb2, b3 = nb3;
            PREF1(jt + 1);
            const float* e4 = efp + jt * 64;
            float4 ea = *(const float4*)(e4);
            float4 eb = *(const float4*)(e4 + 4);
            float4 ec = *(const float4*)(e4 + 8);
            float4 ed = *(const float4*)(e4 + 12);
            const int bb = u * 8;
            union { bh8 v; unsigned u32[4]; } pk;
            {
                float p0 = bmask(fmaxf(A * ea.x, B * ea.y), mdw, bb + 0);
                float p1 = bmask(fmaxf(A * ea.z, B * ea.w), mdw, bb + 1);
                pk.u32[0] = __builtin_amdgcn_perm(__builtin_bit_cast(unsigned, p1),
                                                  __builtin_bit_cast(unsigned, p0), 0x07060302u);
                float p2 = bmask(fmaxf(A * eb.x, B * eb.y), mdw, bb + 2);
                float p3 = bmask(fmaxf(A * eb.z, B * eb.w), mdw, bb + 3);
                pk.u32[1] = __builtin_amdgcn_perm(__builtin_bit_cast(unsigned, p3),
                                                  __builtin_bit_cast(unsigned, p2), 0x07060302u);
                float p4 = bmask(fmaxf(A * ec.x, B * ec.y), mdw, bb + 4);
                float p5 = bmask(fmaxf(A * ec.z, B * ec.w), mdw, bb + 5);
                pk.u32[2] = __builtin_amdgcn_perm(__builtin_bit_cast(unsigned, p5),
                                                  __builtin_bit_cast(unsigned, p4), 0x07060302u);
                float p6 = bmask(fmaxf(A * ed.x, B * ed.y), mdw, bb + 6);
                float p7 = bmask(fmaxf(A * ed.z, B * ed.w), mdw, bb + 7);
                pk.u32[3] = __builtin_amdgcn_perm(__builtin_bit_cast(unsigned, p7),
                                                  __builtin_bit_cast(unsigned, p6), 0x07060302u);
            }
            acc0 = __builtin_amdgcn_mfma_f32_16x16x32_bf16(pk.v, b0, acc0, 0, 0, 0);
            acc1 = __builtin_amdgcn_mfma_f32_16x16x32_bf16(pk.v, b1, acc1, 0, 0, 0);
            acc2 = __builtin_amdgcn_mfma_f32_16x16x32_bf16(pk.v, b2, acc2, 0, 0, 0);
            acc3 = __builtin_amdgcn_mfma_f32_16x16x32_bf16(pk.v, b3, acc3, 0, 0, 0);
            accd = __builtin_amdgcn_mfma_f32_16x16x32_bf16(pk.v, ones, accd, 0, 0, 0);
        }
    }
#undef PREF1
    __syncthreads();                 // done reading EFs
    float (*comb)[64][21] = (float(*)[64][21])EFs;   // 21-pad: conflict-free
    if (jq == 1) {
        float* cb = &comb[rowg][lane][0];
#pragma unroll
        for (int r = 0; r < 4; ++r) {
            cb[r] = acc0[r]; cb[4 + r] = acc1[r]; cb[8 + r] = acc2[r];
            cb[12 + r] = acc3[r]; cb[16 + r] = accd[r];
        }
    }
    __syncthreads();
    if (jq == 0) {
        const float* cb = &comb[rowg][lane][0];
#pragma unroll
        for (int r = 0; r < 4; ++r) {
            acc0[r] += cb[r]; acc1[r] += cb[4 + r]; acc2[r] += cb[8 + r];
            acc3[r] += cb[12 + r]; accd[r] += cb[16 + r];
        }
#pragma unroll
        for (int r = 0; r < 4; ++r) {
            const float den = __shfl(accd[r], lane & 48);
            const float inv = 1.0f / den;
            unsigned short* o = x2b + (size_t)(i0 + rowg * 16 + grp * 4 + r) * NF + h * 64 + r16;
            o[0]  = f2bu(elu1(acc0[r] * inv));
            o[16] = f2bu(elu1(acc1[r] * inv));
            o[32] = f2bu(elu1(acc2[r] * inv));
            o[48] = f2bu(elu1(acc3[r] * inv));
        }
    }
}

// ---------------- attn layer 2: single pass, fused elu + log_softmax ----------------
// block = 16 rows x all 4096 j; 8 waves split j 8-way; LDS tree combine
__global__ __launch_bounds__(512, 6) void attn2_k(const unsigned short* __restrict__ Bp2,
                                                  const unsigned* __restrict__ adjq,
                                                  const float* __restrict__ f12L,
                                                  const float* __restrict__ f22L,
                                                  const unsigned* __restrict__ FM2u,
                                                  float* __restrict__ out) {
    __shared__ float EFs[8192];          // 32 KiB
    __shared__ float comb[8][64][17];    // 34.8 KiB
    const int tid = threadIdx.x, w = tid >> 6, lane = tid & 63;
    const int r16 = lane & 15, grp = lane >> 4;
    const int i0 = blockIdx.x * 16;
    const int i = i0 + r16;
    // coalesced adj: 4 dwords for this wave's 16 jt
    const unsigned* adjl = adjq + (size_t)(i0 >> 6) * 8192 + ((i0 & 63) + r16) * 4 + grp;
    unsigned m0 = adjl[(size_t)(w * 4 + 0) * 256];
    unsigned m1 = adjl[(size_t)(w * 4 + 1) * 256];
    unsigned m2 = adjl[(size_t)(w * 4 + 2) * 256];
    unsigned m3 = adjl[(size_t)(w * 4 + 3) * 256];
    const float fm = fdec(FM2u[0]);
    for (int t = 0; t < 8; ++t) {
        int j = tid + t * 512;
        float d = f22L[j] - fm;
        EFs[2 * j] = exp2fast(d);
        EFs[2 * j + 1] = exp2fast(0.2f * d);
    }
    const float f1v = f12L[i];
    const float mL = lrelu(f1v + fm);
    const float A = exp2fast(f1v + fm - mL);
    const float B = exp2fast(__builtin_fmaf(0.2f, f1v + fm, -mL));
    __syncthreads();
    const int jt0 = w * 16;
    f32x4 acc0 = {0,0,0,0}, acc1 = {0,0,0,0}, acc2 = {0,0,0,0}, accd = {0,0,0,0};
    const short ov = (r16 == 0) ? (short)0x3F80 : (short)0;
    bh8 ones;
#pragma unroll
    for (int e = 0; e < 8; ++e) ones[e] = ov;
    const unsigned short* Bbase = Bp2 + lane * 8;
    const float* efp = EFs + grp * 16;
    bh8 nb0, nb1, nb2;
#define PREF2(JT) { const unsigned short* Bn = Bbase + (size_t)(JT) * 1536;              \
        nb0 = *(const bh8*)(Bn); nb1 = *(const bh8*)(Bn + 512); nb2 = *(const bh8*)(Bn + 1024); }
    PREF2(jt0);
#pragma unroll
    for (int q = 0; q < 4; ++q) {
        const unsigned mdw = (q == 0) ? m0 : (q == 1) ? m1 : (q == 2) ? m2 : m3;
#pragma unroll
        for (int u = 0; u < 4; ++u) {
            const int jt = jt0 + q * 4 + u;
            bh8 b0 = nb0, b1 = nb1, b2 = nb2;
            PREF2(jt + 1);
            const float* e4 = efp + jt * 64;
            float4 ea = *(const float4*)(e4);
            float4 eb = *(const float4*)(e4 + 4);
            float4 ec = *(const float4*)(e4 + 8);
            float4 ed = *(const float4*)(e4 + 12);
            const int bb = u * 8;
            union { bh8 v; unsigned u32[4]; } pk;
            {
                float p0 = bmask(fmaxf(A * ea.x, B * ea.y), mdw, bb + 0);
                float p1 = bmask(fmaxf(A * ea.z, B * ea.w), mdw, bb + 1);
                pk.u32[0] = __builtin_amdgcn_perm(__builtin_bit_cast(unsigned, p1),
                                                  __builtin_bit_cast(unsigned, p0), 0x07060302u);
                float p2 = bmask(fmaxf(A * eb.x, B * eb.y), mdw, bb + 2);
                float p3 = bmask(fmaxf(A * eb.z, B * eb.w), mdw, bb + 3);
                pk.u32[1] = __builtin_amdgcn_perm(__builtin_bit_cast(unsigned, p3),
                                                  __builtin_bit_cast(unsigned, p2), 0x07060302u);
                float p4 = bmask(fmaxf(A * ec.x, B * ec.y), mdw, bb + 4);
                float p5 = bmask(fmaxf(A * ec.z, B * ec.w), mdw, bb + 5);
                pk.u32[2] = __builtin_amdgcn_perm(__builtin_bit_cast(unsigned, p5),
                                                  __builtin_bit_cast(unsigned, p4), 0x07060302u);
                float p6 = bmask(fmaxf(A * ed.x, B * ed.y), mdw, bb + 6);
                float p7 = bmask(fmaxf(A * ed.z, B * ed.w), mdw, bb + 7);
                pk.u32[3] = __builtin_amdgcn_perm(__builtin_bit_cast(unsigned, p7),
                                                  __builtin_bit_cast(unsigned, p6), 0x07060302u);
            }
            acc0 = __builtin_amdgcn_mfma_f32_16x16x32_bf16(pk.v, b0, acc0, 0, 0, 0);
            acc1 = __builtin_amdgcn_mfma_f32_16x16x32_bf16(pk.v, b1, acc1, 0, 0, 0);
            acc2 = __builtin_amdgcn_mfma_f32_16x16x32_bf16(pk.v, b2, acc2, 0, 0, 0);
            accd = __builtin_amdgcn_mfma_f32_16x16x32_bf16(pk.v, ones, accd, 0, 0, 0);
        }
    }
#undef PREF2
    // tree combine over 8 waves
    {
        float* cb = &comb[w][lane][0];
#pragma unroll
        for (int r = 0; r < 4; ++r) {
            cb[r] = acc0[r]; cb[4 + r] = acc1[r]; cb[8 + r] = acc2[r]; cb[12 + r] = accd[r];
        }
    }
    __syncthreads();
    if (w < 4) {
        const float* sb = &comb[w + 4][lane][0];
        float* cb = &comb[w][lane][0];
#pragma unroll
        for (int r = 0; r < 4; ++r) {
            acc0[r] += sb[r]; acc1[r] += sb[4 + r]; acc2[r] += sb[8 + r]; accd[r] += sb[12 + r];
            cb[r] = acc0[r]; cb[4 + r] = acc1[r]; cb[8 + r] = acc2[r]; cb[12 + r] = accd[r];
        }
    }
    __syncthreads();
    if (w < 2) {
        const float* sb = &comb[w + 2][lane][0];
        float* cb = &comb[w][lane][0];
#pragma unroll
        for (int r = 0; r < 4; ++r) {
            acc0[r] += sb[r]; acc1[r] += sb[4 + r]; acc2[r] += sb[8 + r]; accd[r] += sb[12 + r];
            cb[r] = acc0[r]; cb[4 + r] = acc1[r]; cb[8 + r] = acc2[r]; cb[12 + r] = accd[r];
        }
    }
    __syncthreads();
    if (w == 0) {
        const float* sb = &comb[1][lane][0];
#pragma unroll
        for (int r = 0; r < 4; ++r) {
            acc0[r] += sb[r]; acc1[r] += sb[4 + r]; acc2[r] += sb[8 + r]; accd[r] += sb[12 + r];
        }
        // finish: denom, elu, log_softmax, write
#pragma unroll
        for (int r = 0; r < 4; ++r) {
            const int row = grp * 4 + r;
            const float den = __shfl(accd[r], lane & 48);
            const float inv = 1.0f / den;
            float v0 = elu1(acc0[r] * inv);
            float v1 = elu1(acc1[r] * inv);
            float v2 = (r16 < 8) ? elu1(acc2[r] * inv) : -3.0e38f;
            float mx = fmaxf(fmaxf(v0, v1), v2);
#pragma unroll
            for (int o = 1; o < 16; o <<= 1) mx = fmaxf(mx, __shfl_xor(mx, o));
            float ex = __expf(v0 - mx) + __expf(v1 - mx) + ((r16 < 8) ? __expf(v2 - mx) : 0.f);
#pragma unroll
            for (int o = 1; o < 16; o <<= 1) ex += __shfl_xor(ex, o);
            const float lse = mx + logf(ex);
            float* op = out + (size_t)(i0 + row) * NCLS;
            op[r16] = v0 - lse;
            op[16 + r16] = v1 - lse;
            if (r16 < 8) op[32 + r16] = v2 - lse;
        }
    }
}

// ---------------- workspace layout (bytes) ----------------
#define OFF_XB   0ULL           // 4096*512*2 = 4194304
#define OFF_WT   4194304ULL     // 512*512*2  = 524288
#define OFF_WOT  4718592ULL     // 48*512*2   = 49152
#define OFF_BP1  4767744ULL     // 8*128*2048*2 = 4194304
#define OFF_X2B  8962048ULL     // 4096*512*2 = 4194304
#define OFF_BP2  13156352ULL    // 128*1536*2 = 393216
#define OFF_F1L  13549568ULL    // 8*4096*4 = 131072
#define OFF_F2L  13680640ULL    // 131072
#define OFF_F12  13811712ULL    // 16384
#define OFF_F22  13828096ULL    // 16384
#define OFF_FM1  13844480ULL    // 256
#define OFF_FM2  13844736ULL    // 256
#define OFF_ADJ  13844992ULL    // adjq: 64*32*64*4*4 = 2097152 -> end 15942144

extern "C" void kernel_launch(void* const* d_in, const int* in_sizes, int n_in,
                              void* d_out, int out_size, void* d_ws, size_t ws_size,
                              hipStream_t stream) {
    const float* x     = (const float*)d_in[0];
    const float* adj   = (const float*)d_in[1];
    const float* Ws    = (const float*)d_in[2];
    const float* a_s   = (const float*)d_in[3];
    const float* W_out = (const float*)d_in[4];
    const float* a_out = (const float*)d_in[5];
    float* out = (float*)d_out;
    char* w = (char*)d_ws;

    unsigned short* xb  = (unsigned short*)(w + OFF_XB);
    unsigned short* WT  = (unsigned short*)(w + OFF_WT);
    unsigned short* WoT = (unsigned short*)(w + OFF_WOT);
    unsigned short* Bp1 = (unsigned short*)(w + OFF_BP1);
    unsigned short* x2b = (unsigned short*)(w + OFF_X2B);
    unsigned short* Bp2 = (unsigned short*)(w + OFF_BP2);
    float* f1L = (float*)(w + OFF_F1L);
    float* f2L = (float*)(w + OFF_F2L);
    float* f12 = (float*)(w + OFF_F12);
    float* f22 = (float*)(w + OFF_F22);
    unsigned* FM1u = (unsigned*)(w + OFF_FM1);
    unsigned* FM2u = (unsigned*)(w + OFF_FM2);
    unsigned* adjq = (unsigned*)(w + OFF_ADJ);

    prep_all_k<<<11360, 256, 0, stream>>>(x, adj, Ws, W_out, xb, WT, WoT, adjq, FM1u, FM2u);
    gemm1_k<<<dim3(32, 8), 512, 0, stream>>>(xb, WT, a_s, Bp1, f1L, f2L, FM1u);
    attn1_k<<<dim3(64, 8), 512, 0, stream>>>(Bp1, adjq, f1L, f2L, FM1u, x2b);
    gemm2_k<<<64, 256, 0, stream>>>(x2b, WoT, a_out, Bp2, f12, f22, FM2u);
    attn2_k<<<256, 512, 0, stream>>>(Bp2, adjq, f12, f22, FM2u, out);
}

// Round 8
// 251.461 us; speedup vs baseline: 1.0807x; 1.0807x over previous
//
#include <hip/hip_runtime.h>
#include <hip/hip_bf16.h>
#include <stdint.h>

#define NN 4096      // nodes
#define NF 512       // NFEAT = NHEADS*NHID
#define NH 64        // NHID
#define NCLS 40      // NCLASS
#define NHEADS 8
#define LOG2E 1.4426950408889634f

typedef __attribute__((ext_vector_type(8))) short bh8;
typedef __attribute__((ext_vector_type(4))) float f32x4;

__device__ __forceinline__ unsigned short f2bu(float f) {
    union { float f; unsigned u; } v; v.f = f;
    unsigned r = (v.u + 0x7FFFu + ((v.u >> 16) & 1u)) >> 16;
    return (unsigned short)r;
}
__device__ __forceinline__ float lrelu(float x) { return fmaxf(x, 0.2f * x); }
__device__ __forceinline__ float elu1(float x) { return x > 0.f ? x : expm1f(x); }
__device__ __forceinline__ float exp2fast(float x) {
    float r; asm("v_exp_f32 %0, %1" : "=v"(r) : "v"(x)); return r;
}
// ordered-uint encode/decode for float atomicMax
__device__ __forceinline__ unsigned fenc(float f) {
    unsigned u = __builtin_bit_cast(unsigned, f);
    return ((int)u < 0) ? ~u : (u | 0x80000000u);
}
__device__ __forceinline__ float fdec(unsigned k) {
    unsigned u = (k & 0x80000000u) ? (k ^ 0x80000000u) : ~k;
    return __builtin_bit_cast(float, u);
}
// 1-bit sign-extended field extract: 0 or 0xFFFFFFFF
__device__ __forceinline__ int sbfe1(unsigned v, int off) {
#if __has_builtin(__builtin_amdgcn_sbfe)
    return __builtin_amdgcn_sbfe((int)v, off, 1);
#else
    return ((int)(v << (31 - off))) >> 31;
#endif
}
__device__ __forceinline__ float bmask(float p, unsigned mdw, int bit) {
    return __builtin_bit_cast(float,
        __builtin_bit_cast(unsigned, p) & (unsigned)sbfe1(mdw, bit));
}
// pack two f32 -> bf16 pair (RN)
__device__ __forceinline__ unsigned pack2(float x, float y) {
    unsigned ux = __builtin_bit_cast(unsigned, x), uy = __builtin_bit_cast(unsigned, y);
    ux += 0x7FFFu + ((ux >> 16) & 1u);
    uy += 0x7FFFu + ((uy >> 16) & 1u);
    return __builtin_amdgcn_perm(uy, ux, 0x07060302u);
}

// ---------------- fused prep: adj bitplanes (byte-plane layout) + x/W bf16 + FM init ----------------
// adjp[(i*4+grp)*128 + jt] bit e = adj[i][jt*32 + grp*8 + e]
// blocks [0,8192): adj (half-row each); [8192,10240): xb; [10240,11264): WT; [11264,11360): WoT
__global__ __launch_bounds__(256) void prep_all_k(const float* __restrict__ x,
                                                  const float* __restrict__ adj,
                                                  const float* __restrict__ Ws,
                                                  const float* __restrict__ Wo,
                                                  unsigned short* __restrict__ xb,
                                                  unsigned short* __restrict__ WT,
                                                  unsigned short* __restrict__ WoT,
                                                  unsigned char* __restrict__ adjp,
                                                  unsigned* __restrict__ FM1u,
                                                  unsigned* __restrict__ FM2u) {
    const int bid = blockIdx.x, tid = threadIdx.x;
    if (bid < 8192) {
        __shared__ unsigned char sm[4][64];
        const int i = bid >> 1, half = bid & 1;
        const float* rp = adj + (size_t)i * NN + half * 2048 + tid * 8;
        float4 v0 = ((const float4*)rp)[0];
        float4 v1 = ((const float4*)rp)[1];
        unsigned b = (v0.x > 0.f ? 1u : 0u) | (v0.y > 0.f ? 2u : 0u) |
                     (v0.z > 0.f ? 4u : 0u) | (v0.w > 0.f ? 8u : 0u) |
                     (v1.x > 0.f ? 16u : 0u) | (v1.y > 0.f ? 32u : 0u) |
                     (v1.z > 0.f ? 64u : 0u) | (v1.w > 0.f ? 128u : 0u);
        sm[tid & 3][tid >> 2] = (unsigned char)b;
        __syncthreads();
        if (tid < 64) {
            int gp = tid >> 4, word = tid & 15;
            unsigned d = *(const unsigned*)&sm[gp][word * 4];
            *(unsigned*)(adjp + ((size_t)i * 4 + gp) * 128 + half * 64 + word * 4) = d;
        }
    } else if (bid < 10240) {
        if (bid == 8192) {
            if (tid < 8) FM1u[tid] = 0u;
            if (tid == 8) FM2u[0] = 0u;
        }
        int t = (bid - 8192) * 256 + tid;
        float4 v = ((const float4*)x)[t];
        uint2 o; o.x = pack2(v.x, v.y); o.y = pack2(v.z, v.w);
        ((uint2*)xb)[t] = o;
    } else if (bid < 11264) {
        int j = (bid - 10240) * 256 + tid;
        int c = j >> 9, k = j & 511;
        WT[j] = f2bu(Ws[(size_t)(c >> 6) * (NF * NH) + (size_t)k * NH + (c & 63)]);
    } else {
        int j = (bid - 11264) * 256 + tid;
        int c = j >> 9, k = j & 511;
        WoT[j] = f2bu(c < NCLS ? Wo[(size_t)k * NCLS + c] : 0.f);
    }
}

// ---------------- GEMM1 (BM=128, 8 waves): Bp1 = pack(x @ Wcat), f1/f2 + FM1 ----------------
__global__ __launch_bounds__(512) void gemm1_k(const unsigned short* __restrict__ xb,
                                               const unsigned short* __restrict__ WT,
                                               const float* __restrict__ a_s,
                                               unsigned short* __restrict__ Bp1,
                                               float* __restrict__ f1L,
                                               float* __restrict__ f2L,
                                               unsigned* __restrict__ FM1u) {
    __shared__ unsigned short xs[128 * 40];
    __shared__ unsigned short wsm[64 * 40];
    const int tid = threadIdx.x;
    const int w = tid >> 6, lane = tid & 63, r16 = lane & 15, grp = lane >> 4;
    const int i0 = blockIdx.x << 7, h = blockIdx.y, c0 = h << 6;
    const int srow = tid >> 2, sseg = tid & 3;
    const unsigned short* xsrc = xb + (size_t)(i0 + srow) * NF + sseg * 8;
    const unsigned short* wsrc = WT + (size_t)(c0 + (srow & 63)) * NF + sseg * 8;
    f32x4 a0 = {0,0,0,0}, a1 = {0,0,0,0}, a2 = {0,0,0,0}, a3 = {0,0,0,0};
    bh8 rx = *(const bh8*)(xsrc);
    bh8 rw; if (tid < 256) rw = *(const bh8*)(wsrc);
    for (int kb = 0; kb < NF; kb += 32) {
        *(bh8*)(xs + srow * 40 + sseg * 8) = rx;
        if (tid < 256) *(bh8*)(wsm + srow * 40 + sseg * 8) = rw;
        __syncthreads();
        if (kb + 32 < NF) {
            rx = *(const bh8*)(xsrc + kb + 32);
            if (tid < 256) rw = *(const bh8*)(wsrc + kb + 32);
        }
        bh8 af = *(const bh8*)(xs + (w * 16 + r16) * 40 + grp * 8);
        bh8 b0 = *(const bh8*)(wsm + (r16) * 40 + grp * 8);
        bh8 b1 = *(const bh8*)(wsm + (16 + r16) * 40 + grp * 8);
        bh8 b2 = *(const bh8*)(wsm + (32 + r16) * 40 + grp * 8);
        bh8 b3 = *(const bh8*)(wsm + (48 + r16) * 40 + grp * 8);
        a0 = __builtin_amdgcn_mfma_f32_16x16x32_bf16(af, b0, a0, 0, 0, 0);
        a1 = __builtin_amdgcn_mfma_f32_16x16x32_bf16(af, b1, a1, 0, 0, 0);
        a2 = __builtin_amdgcn_mfma_f32_16x16x32_bf16(af, b2, a2, 0, 0, 0);
        a3 = __builtin_amdgcn_mfma_f32_16x16x32_bf16(af, b3, a3, 0, 0, 0);
        __syncthreads();
    }
    // direct B-panel write
    const int jt = (i0 >> 5) + (w >> 1);
    const int kg = ((w & 1) << 1) + (grp >> 1);
    const int lanep = kg * 16 + r16;
    const int ebase = (grp & 1) * 4;
    unsigned short* bp = Bp1 + ((size_t)(h * 128 + jt)) * 2048 + lanep * 8 + ebase;
    {
        uint2 v;
        v.x = pack2(a0[0], a0[1]); v.y = pack2(a0[2], a0[3]); *(uint2*)(bp + 0 * 512) = v;
        v.x = pack2(a1[0], a1[1]); v.y = pack2(a1[2], a1[3]); *(uint2*)(bp + 1 * 512) = v;
        v.x = pack2(a2[0], a2[1]); v.y = pack2(a2[2], a2[3]); *(uint2*)(bp + 2 * 512) = v;
        v.x = pack2(a3[0], a3[1]); v.y = pack2(a3[2], a3[3]); *(uint2*)(bp + 3 * 512) = v;
    }
    const float* ap = a_s + h * 128;
    float a1v[4], a2v[4];
#pragma unroll
    for (int n = 0; n < 4; ++n) { a1v[n] = ap[r16 + 16 * n]; a2v[n] = ap[64 + r16 + 16 * n]; }
    float wmax = -3.0e38f;
#pragma unroll
    for (int r = 0; r < 4; ++r) {
        const int orow = i0 + w * 16 + grp * 4 + r;
        float s1 = a0[r] * a1v[0] + a1[r] * a1v[1] + a2[r] * a1v[2] + a3[r] * a1v[3];
        float s2 = a0[r] * a2v[0] + a1[r] * a2v[1] + a2[r] * a2v[2] + a3[r] * a2v[3];
#pragma unroll
        for (int o2 = 1; o2 < 16; o2 <<= 1) { s1 += __shfl_xor(s1, o2); s2 += __shfl_xor(s2, o2); }
        s1 *= LOG2E; s2 *= LOG2E;
        if (r16 == 0) { f1L[h * NN + orow] = s1; f2L[h * NN + orow] = s2; }
        wmax = fmaxf(wmax, s2);
    }
    wmax = fmaxf(wmax, __shfl_xor(wmax, 16));
    wmax = fmaxf(wmax, __shfl_xor(wmax, 32));
    if (lane == 0) atomicMax(&FM1u[h], fenc(wmax));
}

// ---------------- GEMM2: Bp2 = pack(x2 @ W_out), f12/f22 + FM2 ----------------
__global__ __launch_bounds__(256) void gemm2_k(const unsigned short* __restrict__ x2b,
                                               const unsigned short* __restrict__ WoT,
                                               const float* __restrict__ a_out,
                                               unsigned short* __restrict__ Bp2,
                                               float* __restrict__ f12L,
                                               float* __restrict__ f22L,
                                               unsigned* __restrict__ FM2u) {
    __shared__ unsigned short xs[64 * 40];
    __shared__ unsigned short wsm[48 * 40];
    const int tid = threadIdx.x;
    const int w = tid >> 6, lane = tid & 63, r16 = lane & 15, grp = lane >> 4;
    const int i0 = blockIdx.x << 6;
    const int srow = tid >> 2, sseg = tid & 3;
    const unsigned short* xsrc = x2b + (size_t)(i0 + srow) * NF + sseg * 8;
    const unsigned short* wsrc = WoT + (size_t)srow * NF + sseg * 8;
    f32x4 a0 = {0,0,0,0}, a1 = {0,0,0,0}, a2 = {0,0,0,0};
    bh8 rx = *(const bh8*)(xsrc);
    bh8 rw; if (tid < 192) rw = *(const bh8*)(wsrc);
    for (int kb = 0; kb < NF; kb += 32) {
        *(bh8*)(xs + srow * 40 + sseg * 8) = rx;
        if (tid < 192) *(bh8*)(wsm + srow * 40 + sseg * 8) = rw;
        __syncthreads();
        if (kb + 32 < NF) {
            rx = *(const bh8*)(xsrc + kb + 32);
            if (tid < 192) rw = *(const bh8*)(wsrc + kb + 32);
        }
        bh8 af = *(const bh8*)(xs + (w * 16 + r16) * 40 + grp * 8);
        bh8 b0 = *(const bh8*)(wsm + (r16) * 40 + grp * 8);
        bh8 b1 = *(const bh8*)(wsm + (16 + r16) * 40 + grp * 8);
        bh8 b2 = *(const bh8*)(wsm + (32 + r16) * 40 + grp * 8);
        a0 = __builtin_amdgcn_mfma_f32_16x16x32_bf16(af, b0, a0, 0, 0, 0);
        a1 = __builtin_amdgcn_mfma_f32_16x16x32_bf16(af, b1, a1, 0, 0, 0);
        a2 = __builtin_amdgcn_mfma_f32_16x16x32_bf16(af, b2, a2, 0, 0, 0);
        __syncthreads();
    }
    const int jt = (i0 >> 5) + (w >> 1);
    const int kg = ((w & 1) << 1) + (grp >> 1);
    const int lanep = kg * 16 + r16;
    const int ebase = (grp & 1) * 4;
    unsigned short* bp = Bp2 + (size_t)jt * 1536 + lanep * 8 + ebase;
    {
        uint2 v;
        v.x = pack2(a0[0], a0[1]); v.y = pack2(a0[2], a0[3]); *(uint2*)(bp + 0 * 512) = v;
        v.x = pack2(a1[0], a1[1]); v.y = pack2(a1[2], a1[3]); *(uint2*)(bp + 1 * 512) = v;
        v.x = pack2(a2[0], a2[1]); v.y = pack2(a2[2], a2[3]); *(uint2*)(bp + 2 * 512) = v;
    }
    float a1v[3], a2v[3];
#pragma unroll
    for (int n = 0; n < 3; ++n) {
        int col = r16 + 16 * n;
        a1v[n] = col < NCLS ? a_out[col] : 0.f;
        a2v[n] = col < NCLS ? a_out[NCLS + col] : 0.f;
    }
    float wmax = -3.0e38f;
#pragma unroll
    for (int r = 0; r < 4; ++r) {
        const int orow = i0 + w * 16 + grp * 4 + r;
        float s1 = a0[r] * a1v[0] + a1[r] * a1v[1] + a2[r] * a1v[2];
        float s2 = a0[r] * a2v[0] + a1[r] * a2v[1] + a2[r] * a2v[2];
#pragma unroll
        for (int o2 = 1; o2 < 16; o2 <<= 1) { s1 += __shfl_xor(s1, o2); s2 += __shfl_xor(s2, o2); }
        s1 *= LOG2E; s2 *= LOG2E;
        if (r16 == 0) { f12L[orow] = s1; f22L[orow] = s2; }
        wmax = fmaxf(wmax, s2);
    }
    wmax = fmaxf(wmax, __shfl_xor(wmax, 16));
    wmax = fmaxf(wmax, __shfl_xor(wmax, 32));
    if (lane == 0) atomicMax(&FM2u[0], fenc(wmax));
}

// ---------------- attn layer 1: ADJd + half-EF in LDS (49 KB -> 3 blocks/CU) ----------------
__global__ __launch_bounds__(512, 6) void attn1_k(const unsigned short* __restrict__ Bp1,
                                                  const unsigned char* __restrict__ adjp,
                                                  const float* __restrict__ f1L,
                                                  const float* __restrict__ f2L,
                                                  const unsigned* __restrict__ FM1u,
                                                  unsigned short* __restrict__ x2b) {
    __shared__ float SH[12544];                 // [0,4096): EF half; [4096,12544): ADJd (pitch 33)
    unsigned* ADJd = (unsigned*)&SH[4096];
    const int tid = threadIdx.x, w = tid >> 6, lane = tid & 63;
    const int r16 = lane & 15, grp = lane >> 4;
    const int rowg = w & 3, jq = w >> 2;
    const int h = blockIdx.y;
    const int i0 = blockIdx.x * 64;
    const float fm = fdec(FM1u[h]);
    const float* f2p = f2L + h * NN;
    // stage adjacency rows [i0, i0+64) once: 8192 dwords, 33-dword pitch (2-way banks on read)
    {
        const unsigned* asrc = (const unsigned*)(adjp + (size_t)i0 * 512);
        for (int t = 0; t < 16; ++t) {
            int idx = tid + t * 512;
            ADJd[(idx >> 5) * 33 + (idx & 31)] = asrc[idx];
        }
    }
    const int irow = i0 + rowg * 16 + r16;
    const float f1v = f1L[h * NN + irow];
    const float mL = lrelu(f1v + fm);
    const float A = exp2fast(f1v + fm - mL);
    const float B = exp2fast(__builtin_fmaf(0.2f, f1v + fm, -mL));
    const unsigned* adjl = ADJd + ((rowg * 16 + r16) * 4 + grp) * 33;
    const unsigned short* Bbase = Bp1 + (size_t)h * 128 * 2048 + lane * 8;
    f32x4 acc0 = {0,0,0,0}, acc1 = {0,0,0,0}, acc2 = {0,0,0,0}, acc3 = {0,0,0,0}, accd = {0,0,0,0};
    const short ov = (r16 == 0) ? (short)0x3F80 : (short)0;
    bh8 ones;
#pragma unroll
    for (int e = 0; e < 8; ++e) ones[e] = ov;
    bh8 nb0, nb1, nb2, nb3;
#define PREF1(JT) { const unsigned short* Bn = Bbase + (size_t)(JT) * 2048;              \
        nb0 = *(const bh8*)(Bn);        nb1 = *(const bh8*)(Bn + 512);                    \
        nb2 = *(const bh8*)(Bn + 1024); nb3 = *(const bh8*)(Bn + 1536); }
    for (int half = 0; half < 2; ++half) {
        // stage EF for this half (2048 j -> 4096 floats)
        for (int t = 0; t < 4; ++t) {
            int jl = tid + t * 512;
            float d = f2p[half * 2048 + jl] - fm;
            SH[2 * jl] = exp2fast(d);
            SH[2 * jl + 1] = exp2fast(0.2f * d);
        }
        __syncthreads();
        const int jt4l0 = jq * 8;                       // local jt4 within half
        PREF1(half * 64 + jt4l0 * 4);
        unsigned nmdw = adjl[half * 16 + jt4l0];
        for (int jt4i = 0; jt4i < 8; ++jt4i) {
            const int jt4l = jt4l0 + jt4i;
            const unsigned mdw = nmdw;
            if (jt4i < 7) nmdw = adjl[half * 16 + jt4l + 1];
#pragma unroll
            for (int u = 0; u < 4; ++u) {
                const int jtl = jt4l * 4 + u;
                bh8 b0 = nb0, b1 = nb1, b2 = nb2, b3 = nb3;
                PREF1(half * 64 + jtl + 1);
                const float* e4 = SH + jtl * 64 + grp * 16;
                float4 ea = *(const float4*)(e4);
                float4 eb = *(const float4*)(e4 + 4);
                float4 ec = *(const float4*)(e4 + 8);
                float4 ed = *(const float4*)(e4 + 12);
                const int bb = u * 8;
                union { bh8 v; unsigned u32[4]; } pk;
                {
                    float p0 = bmask(fmaxf(A * ea.x, B * ea.y), mdw, bb + 0);
                    float p1 = bmask(fmaxf(A * ea.z, B * ea.w), mdw, bb + 1);
                    pk.u32[0] = __builtin_amdgcn_perm(__builtin_bit_cast(unsigned, p1),
                                                      __builtin_bit_cast(unsigned, p0), 0x07060302u);
                    float p2 = bmask(fmaxf(A * eb.x, B * eb.y), mdw, bb + 2);
                    float p3 = bmask(fmaxf(A * eb.z, B * eb.w), mdw, bb + 3);
                    pk.u32[1] = __builtin_amdgcn_perm(__builtin_bit_cast(unsigned, p3),
                                                      __builtin_bit_cast(unsigned, p2), 0x07060302u);
                    float p4 = bmask(fmaxf(A * ec.x, B * ec.y), mdw, bb + 4);
                    float p5 = bmask(fmaxf(A * ec.z, B * ec.w), mdw, bb + 5);
                    pk.u32[2] = __builtin_amdgcn_perm(__builtin_bit_cast(unsigned, p5),
                                                      __builtin_bit_cast(unsigned, p4), 0x07060302u);
                    float p6 = bmask(fmaxf(A * ed.x, B * ed.y), mdw, bb + 6);
                    float p7 = bmask(fmaxf(A * ed.z, B * ed.w), mdw, bb + 7);
                    pk.u32[3] = __builtin_amdgcn_perm(__builtin_bit_cast(unsigned, p7),
                                                      __builtin_bit_cast(unsigned, p6), 0x07060302u);
                }
                acc0 = __builtin_amdgcn_mfma_f32_16x16x32_bf16(pk.v, b0, acc0, 0, 0, 0);
                acc1 = __builtin_amdgcn_mfma_f32_16x16x32_bf16(pk.v, b1, acc1, 0, 0, 0);
                acc2 = __builtin_amdgcn_mfma_f32_16x16x32_bf16(pk.v, b2, acc2, 0, 0, 0);
                acc3 = __builtin_amdgcn_mfma_f32_16x16x32_bf16(pk.v, b3, acc3, 0, 0, 0);
                accd = __builtin_amdgcn_mfma_f32_16x16x32_bf16(pk.v, ones, accd, 0, 0, 0);
            }
        }
        __syncthreads();               // done reading this half's EF (and, after half 1, ADJd)
    }
#undef PREF1
    float (*comb)[64][21] = (float(*)[64][21])SH;   // overlay (5376 floats < 12544)
    if (jq == 1) {
        float* cb = &comb[rowg][lane][0];
#pragma unroll
        for (int r = 0; r < 4; ++r) {
            cb[r] = acc0[r]; cb[4 + r] = acc1[r]; cb[8 + r] = acc2[r];
            cb[12 + r] = acc3[r]; cb[16 + r] = accd[r];
        }
    }
    __syncthreads();
    if (jq == 0) {
        const float* cb = &comb[rowg][lane][0];
#pragma unroll
        for (int r = 0; r < 4; ++r) {
            acc0[r] += cb[r]; acc1[r] += cb[4 + r]; acc2[r] += cb[8 + r];
            acc3[r] += cb[12 + r]; accd[r] += cb[16 + r];
        }
#pragma unroll
        for (int r = 0; r < 4; ++r) {
            const float den = __shfl(accd[r], lane & 48);
            const float inv = 1.0f / den;
            unsigned short* o = x2b + (size_t)(i0 + rowg * 16 + grp * 4 + r) * NF + h * 64 + r16;
            o[0]  = f2bu(elu1(acc0[r] * inv));
            o[16] = f2bu(elu1(acc1[r] * inv));
            o[32] = f2bu(elu1(acc2[r] * inv));
            o[48] = f2bu(elu1(acc3[r] * inv));
        }
    }
}

// ---------------- attn layer 2: single pass, fused elu + log_softmax ----------------
// block = 16 rows x all 4096 j; 8 waves split j 8-way; LDS tree combine
__global__ __launch_bounds__(512, 6) void attn2_k(const unsigned short* __restrict__ Bp2,
                                                  const unsigned char* __restrict__ adjp,
                                                  const float* __restrict__ f12L,
                                                  const float* __restrict__ f22L,
                                                  const unsigned* __restrict__ FM2u,
                                                  float* __restrict__ out) {
    __shared__ float EFs[8192];          // 32 KiB
    __shared__ float comb[8][64][17];    // 34.8 KiB
    const int tid = threadIdx.x, w = tid >> 6, lane = tid & 63;
    const int r16 = lane & 15, grp = lane >> 4;
    const int i0 = blockIdx.x * 16;
    const int i = i0 + r16;
    const float fm = fdec(FM2u[0]);
    for (int t = 0; t < 8; ++t) {
        int j = tid + t * 512;
        float d = f22L[j] - fm;
        EFs[2 * j] = exp2fast(d);
        EFs[2 * j + 1] = exp2fast(0.2f * d);
    }
    const float f1v = f12L[i];
    const float mL = lrelu(f1v + fm);
    const float A = exp2fast(f1v + fm - mL);
    const float B = exp2fast(__builtin_fmaf(0.2f, f1v + fm, -mL));
    __syncthreads();
    const int jt0 = w * 16;
    const uint4 a4 = *(const uint4*)(adjp + ((size_t)i * 4 + grp) * 128 + jt0);
    f32x4 acc0 = {0,0,0,0}, acc1 = {0,0,0,0}, acc2 = {0,0,0,0}, accd = {0,0,0,0};
    const short ov = (r16 == 0) ? (short)0x3F80 : (short)0;
    bh8 ones;
#pragma unroll
    for (int e = 0; e < 8; ++e) ones[e] = ov;
    const unsigned short* Bbase = Bp2 + lane * 8;
    const float* efp = EFs + grp * 16;
    bh8 nb0, nb1, nb2;
#define PREF2(JT) { const unsigned short* Bn = Bbase + (size_t)(JT) * 1536;              \
        nb0 = *(const bh8*)(Bn); nb1 = *(const bh8*)(Bn + 512); nb2 = *(const bh8*)(Bn + 1024); }
    PREF2(jt0);
#pragma unroll
    for (int q = 0; q < 4; ++q) {
        const unsigned mdw = (q == 0) ? a4.x : (q == 1) ? a4.y : (q == 2) ? a4.z : a4.w;
#pragma unroll
        for (int u = 0; u < 4; ++u) {
            const int jt = jt0 + q * 4 + u;
            bh8 b0 = nb0, b1 = nb1, b2 = nb2;
            PREF2(jt + 1);
            const float* e4 = efp + jt * 64;
            float4 ea = *(const float4*)(e4);
            float4 eb = *(const float4*)(e4 + 4);
            float4 ec = *(const float4*)(e4 + 8);
            float4 ed = *(const float4*)(e4 + 12);
            const int bb = u * 8;
            union { bh8 v; unsigned u32[4]; } pk;
            {
                float p0 = bmask(fmaxf(A * ea.x, B * ea.y), mdw, bb + 0);
                float p1 = bmask(fmaxf(A * ea.z, B * ea.w), mdw, bb + 1);
                pk.u32[0] = __builtin_amdgcn_perm(__builtin_bit_cast(unsigned, p1),
                                                  __builtin_bit_cast(unsigned, p0), 0x07060302u);
                float p2 = bmask(fmaxf(A * eb.x, B * eb.y), mdw, bb + 2);
                float p3 = bmask(fmaxf(A * eb.z, B * eb.w), mdw, bb + 3);
                pk.u32[1] = __builtin_amdgcn_perm(__builtin_bit_cast(unsigned, p3),
                                                  __builtin_bit_cast(unsigned, p2), 0x07060302u);
                float p4 = bmask(fmaxf(A * ec.x, B * ec.y), mdw, bb + 4);
                float p5 = bmask(fmaxf(A * ec.z, B * ec.w), mdw, bb + 5);
                pk.u32[2] = __builtin_amdgcn_perm(__builtin_bit_cast(unsigned, p5),
                                                  __builtin_bit_cast(unsigned, p4), 0x07060302u);
                float p6 = bmask(fmaxf(A * ed.x, B * ed.y), mdw, bb + 6);
                float p7 = bmask(fmaxf(A * ed.z, B * ed.w), mdw, bb + 7);
                pk.u32[3] = __builtin_amdgcn_perm(__builtin_bit_cast(unsigned, p7),
                                                  __builtin_bit_cast(unsigned, p6), 0x07060302u);
            }
            acc0 = __builtin_amdgcn_mfma_f32_16x16x32_bf16(pk.v, b0, acc0, 0, 0, 0);
            acc1 = __builtin_amdgcn_mfma_f32_16x16x32_bf16(pk.v, b1, acc1, 0, 0, 0);
            acc2 = __builtin_amdgcn_mfma_f32_16x16x32_bf16(pk.v, b2, acc2, 0, 0, 0);
            accd = __builtin_amdgcn_mfma_f32_16x16x32_bf16(pk.v, ones, accd, 0, 0, 0);
        }
    }
#undef PREF2
    // tree combine over 8 waves
    {
        float* cb = &comb[w][lane][0];
#pragma unroll
        for (int r = 0; r < 4; ++r) {
            cb[r] = acc0[r]; cb[4 + r] = acc1[r]; cb[8 + r] = acc2[r]; cb[12 + r] = accd[r];
        }
    }
    __syncthreads();
    if (w < 4) {
        const float* sb = &comb[w + 4][lane][0];
        float* cb = &comb[w][lane][0];
#pragma unroll
        for (int r = 0; r < 4; ++r) {
            acc0[r] += sb[r]; acc1[r] += sb[4 + r]; acc2[r] += sb[8 + r]; accd[r] += sb[12 + r];
            cb[r] = acc0[r]; cb[4 + r] = acc1[r]; cb[8 + r] = acc2[r]; cb[12 + r] = accd[r];
        }
    }
    __syncthreads();
    if (w < 2) {
        const float* sb = &comb[w + 2][lane][0];
        float* cb = &comb[w][lane][0];
#pragma unroll
        for (int r = 0; r < 4; ++r) {
            acc0[r] += sb[r]; acc1[r] += sb[4 + r]; acc2[r] += sb[8 + r]; accd[r] += sb[12 + r];
            cb[r] = acc0[r]; cb[4 + r] = acc1[r]; cb[8 + r] = acc2[r]; cb[12 + r] = accd[r];
        }
    }
    __syncthreads();
    if (w == 0) {
        const float* sb = &comb[1][lane][0];
#pragma unroll
        for (int r = 0; r < 4; ++r) {
            acc0[r] += sb[r]; acc1[r] += sb[4 + r]; acc2[r] += sb[8 + r]; accd[r] += sb[12 + r];
        }
        // finish: denom, elu, log_softmax, write
#pragma unroll
        for (int r = 0; r < 4; ++r) {
            const int row = grp * 4 + r;
            const float den = __shfl(accd[r], lane & 48);
            const float inv = 1.0f / den;
            float v0 = elu1(acc0[r] * inv);
            float v1 = elu1(acc1[r] * inv);
            float v2 = (r16 < 8) ? elu1(acc2[r] * inv) : -3.0e38f;
            float mx = fmaxf(fmaxf(v0, v1), v2);
#pragma unroll
            for (int o = 1; o < 16; o <<= 1) mx = fmaxf(mx, __shfl_xor(mx, o));
            float ex = __expf(v0 - mx) + __expf(v1 - mx) + ((r16 < 8) ? __expf(v2 - mx) : 0.f);
#pragma unroll
            for (int o = 1; o < 16; o <<= 1) ex += __shfl_xor(ex, o);
            const float lse = mx + logf(ex);
            float* op = out + (size_t)(i0 + row) * NCLS;
            op[r16] = v0 - lse;
            op[16 + r16] = v1 - lse;
            if (r16 < 8) op[32 + r16] = v2 - lse;
        }
    }
}

// ---------------- workspace layout (bytes) ----------------
#define OFF_XB   0ULL           // 4096*512*2 = 4194304
#define OFF_WT   4194304ULL     // 512*512*2  = 524288
#define OFF_WOT  4718592ULL     // 48*512*2   = 49152
#define OFF_BP1  4767744ULL     // 8*128*2048*2 = 4194304
#define OFF_X2B  8962048ULL     // 4096*512*2 = 4194304
#define OFF_BP2  13156352ULL    // 128*1536*2 = 393216
#define OFF_F1L  13549568ULL    // 8*4096*4 = 131072
#define OFF_F2L  13680640ULL    // 131072
#define OFF_F12  13811712ULL    // 16384
#define OFF_F22  13828096ULL    // 16384
#define OFF_FM1  13844480ULL    // 256
#define OFF_FM2  13844736ULL    // 256
#define OFF_ADJ  13844992ULL    // 4096*4*128 = 2097152 -> end 15942144

extern "C" void kernel_launch(void* const* d_in, const int* in_sizes, int n_in,
                              void* d_out, int out_size, void* d_ws, size_t ws_size,
                              hipStream_t stream) {
    const float* x     = (const float*)d_in[0];
    const float* adj   = (const float*)d_in[1];
    const float* Ws    = (const float*)d_in[2];
    const float* a_s   = (const float*)d_in[3];
    const float* W_out = (const float*)d_in[4];
    const float* a_out = (const float*)d_in[5];
    float* out = (float*)d_out;
    char* w = (char*)d_ws;

    unsigned short* xb  = (unsigned short*)(w + OFF_XB);
    unsigned short* WT  = (unsigned short*)(w + OFF_WT);
    unsigned short* WoT = (unsigned short*)(w + OFF_WOT);
    unsigned short* Bp1 = (unsigned short*)(w + OFF_BP1);
    unsigned short* x2b = (unsigned short*)(w + OFF_X2B);
    unsigned short* Bp2 = (unsigned short*)(w + OFF_BP2);
    float* f1L = (float*)(w + OFF_F1L);
    float* f2L = (float*)(w + OFF_F2L);
    float* f12 = (float*)(w + OFF_F12);
    float* f22 = (float*)(w + OFF_F22);
    unsigned* FM1u = (unsigned*)(w + OFF_FM1);
    unsigned* FM2u = (unsigned*)(w + OFF_FM2);
    unsigned char* adjp = (unsigned char*)(w + OFF_ADJ);

    prep_all_k<<<11360, 256, 0, stream>>>(x, adj, Ws, W_out, xb, WT, WoT, adjp, FM1u, FM2u);
    gemm1_k<<<dim3(32, 8), 512, 0, stream>>>(xb, WT, a_s, Bp1, f1L, f2L, FM1u);
    attn1_k<<<dim3(64, 8), 512, 0, stream>>>(Bp1, adjp, f1L, f2L, FM1u, x2b);
    gemm2_k<<<64, 256, 0, stream>>>(x2b, WoT, a_out, Bp2, f12, f22, FM2u);
    attn2_k<<<256, 512, 0, stream>>>(Bp2, adjp, f12, f22, FM2u, out);
}

// Round 9
// 195.134 us; speedup vs baseline: 1.3927x; 1.2887x over previous
//
#include <hip/hip_runtime.h>
#include <hip/hip_bf16.h>
#include <stdint.h>

#define NN 4096      // nodes
#define NF 512       // NFEAT = NHEADS*NHID
#define NH 64        // NHID
#define NCLS 40      // NCLASS
#define NHEADS 8
#define LOG2E 1.4426950408889634f

typedef __attribute__((ext_vector_type(8))) short bh8;
typedef __attribute__((ext_vector_type(4))) float f32x4;

__device__ __forceinline__ unsigned short f2bu(float f) {
    union { float f; unsigned u; } v; v.f = f;
    unsigned r = (v.u + 0x7FFFu + ((v.u >> 16) & 1u)) >> 16;
    return (unsigned short)r;
}
__device__ __forceinline__ float lrelu(float x) { return fmaxf(x, 0.2f * x); }
__device__ __forceinline__ float elu1(float x) { return x > 0.f ? x : expm1f(x); }
__device__ __forceinline__ float exp2fast(float x) {
    float r; asm("v_exp_f32 %0, %1" : "=v"(r) : "v"(x)); return r;
}
// ordered-uint encode/decode for float atomicMax
__device__ __forceinline__ unsigned fenc(float f) {
    unsigned u = __builtin_bit_cast(unsigned, f);
    return ((int)u < 0) ? ~u : (u | 0x80000000u);
}
__device__ __forceinline__ float fdec(unsigned k) {
    unsigned u = (k & 0x80000000u) ? (k ^ 0x80000000u) : ~k;
    return __builtin_bit_cast(float, u);
}
// 1-bit sign-extended field extract: 0 or 0xFFFFFFFF
__device__ __forceinline__ int sbfe1(unsigned v, int off) {
#if __has_builtin(__builtin_amdgcn_sbfe)
    return __builtin_amdgcn_sbfe((int)v, off, 1);
#else
    return ((int)(v << (31 - off))) >> 31;
#endif
}
__device__ __forceinline__ float bmask(float p, unsigned mdw, int bit) {
    return __builtin_bit_cast(float,
        __builtin_bit_cast(unsigned, p) & (unsigned)sbfe1(mdw, bit));
}
// pack two f32 -> bf16 pair (RN)
__device__ __forceinline__ unsigned pack2(float x, float y) {
    unsigned ux = __builtin_bit_cast(unsigned, x), uy = __builtin_bit_cast(unsigned, y);
    ux += 0x7FFFu + ((ux >> 16) & 1u);
    uy += 0x7FFFu + ((uy >> 16) & 1u);
    return __builtin_amdgcn_perm(uy, ux, 0x07060302u);
}

// ---------------- fused prep: adj bitplanes (byte-plane layout) + x/W bf16 + FM init ----------------
// adjp[(i*4+grp)*128 + jt] bit e = adj[i][jt*32 + grp*8 + e]
// blocks [0,8192): adj (half-row each); [8192,10240): xb; [10240,11264): WT; [11264,11360): WoT
__global__ __launch_bounds__(256) void prep_all_k(const float* __restrict__ x,
                                                  const float* __restrict__ adj,
                                                  const float* __restrict__ Ws,
                                                  const float* __restrict__ Wo,
                                                  unsigned short* __restrict__ xb,
                                                  unsigned short* __restrict__ WT,
                                                  unsigned short* __restrict__ WoT,
                                                  unsigned char* __restrict__ adjp,
                                                  unsigned* __restrict__ FM1u,
                                                  unsigned* __restrict__ FM2u) {
    const int bid = blockIdx.x, tid = threadIdx.x;
    if (bid < 8192) {
        __shared__ unsigned char sm[4][64];
        const int i = bid >> 1, half = bid & 1;
        const float* rp = adj + (size_t)i * NN + half * 2048 + tid * 8;
        float4 v0 = ((const float4*)rp)[0];
        float4 v1 = ((const float4*)rp)[1];
        unsigned b = (v0.x > 0.f ? 1u : 0u) | (v0.y > 0.f ? 2u : 0u) |
                     (v0.z > 0.f ? 4u : 0u) | (v0.w > 0.f ? 8u : 0u) |
                     (v1.x > 0.f ? 16u : 0u) | (v1.y > 0.f ? 32u : 0u) |
                     (v1.z > 0.f ? 64u : 0u) | (v1.w > 0.f ? 128u : 0u);
        sm[tid & 3][tid >> 2] = (unsigned char)b;
        __syncthreads();
        if (tid < 64) {
            int gp = tid >> 4, word = tid & 15;
            unsigned d = *(const unsigned*)&sm[gp][word * 4];
            *(unsigned*)(adjp + ((size_t)i * 4 + gp) * 128 + half * 64 + word * 4) = d;
        }
    } else if (bid < 10240) {
        if (bid == 8192) {
            if (tid < 8) FM1u[tid] = 0u;
            if (tid == 8) FM2u[0] = 0u;
        }
        int t = (bid - 8192) * 256 + tid;
        float4 v = ((const float4*)x)[t];
        uint2 o; o.x = pack2(v.x, v.y); o.y = pack2(v.z, v.w);
        ((uint2*)xb)[t] = o;
    } else if (bid < 11264) {
        int j = (bid - 10240) * 256 + tid;
        int c = j >> 9, k = j & 511;
        WT[j] = f2bu(Ws[(size_t)(c >> 6) * (NF * NH) + (size_t)k * NH + (c & 63)]);
    } else {
        int j = (bid - 11264) * 256 + tid;
        int c = j >> 9, k = j & 511;
        WoT[j] = f2bu(c < NCLS ? Wo[(size_t)k * NCLS + c] : 0.f);
    }
}

// ---------------- GEMM1 (BM=128, 8 waves): Bp1 = pack(x @ Wcat), f1/f2 + FM1 ----------------
__global__ __launch_bounds__(512) void gemm1_k(const unsigned short* __restrict__ xb,
                                               const unsigned short* __restrict__ WT,
                                               const float* __restrict__ a_s,
                                               unsigned short* __restrict__ Bp1,
                                               float* __restrict__ f1L,
                                               float* __restrict__ f2L,
                                               unsigned* __restrict__ FM1u) {
    __shared__ unsigned short xs[128 * 40];
    __shared__ unsigned short wsm[64 * 40];
    const int tid = threadIdx.x;
    const int w = tid >> 6, lane = tid & 63, r16 = lane & 15, grp = lane >> 4;
    const int i0 = blockIdx.x << 7, h = blockIdx.y, c0 = h << 6;
    const int srow = tid >> 2, sseg = tid & 3;
    const unsigned short* xsrc = xb + (size_t)(i0 + srow) * NF + sseg * 8;
    const unsigned short* wsrc = WT + (size_t)(c0 + (srow & 63)) * NF + sseg * 8;
    f32x4 a0 = {0,0,0,0}, a1 = {0,0,0,0}, a2 = {0,0,0,0}, a3 = {0,0,0,0};
    bh8 rx = *(const bh8*)(xsrc);
    bh8 rw; if (tid < 256) rw = *(const bh8*)(wsrc);
    for (int kb = 0; kb < NF; kb += 32) {
        *(bh8*)(xs + srow * 40 + sseg * 8) = rx;
        if (tid < 256) *(bh8*)(wsm + srow * 40 + sseg * 8) = rw;
        __syncthreads();
        if (kb + 32 < NF) {
            rx = *(const bh8*)(xsrc + kb + 32);
            if (tid < 256) rw = *(const bh8*)(wsrc + kb + 32);
        }
        bh8 af = *(const bh8*)(xs + (w * 16 + r16) * 40 + grp * 8);
        bh8 b0 = *(const bh8*)(wsm + (r16) * 40 + grp * 8);
        bh8 b1 = *(const bh8*)(wsm + (16 + r16) * 40 + grp * 8);
        bh8 b2 = *(const bh8*)(wsm + (32 + r16) * 40 + grp * 8);
        bh8 b3 = *(const bh8*)(wsm + (48 + r16) * 40 + grp * 8);
        a0 = __builtin_amdgcn_mfma_f32_16x16x32_bf16(af, b0, a0, 0, 0, 0);
        a1 = __builtin_amdgcn_mfma_f32_16x16x32_bf16(af, b1, a1, 0, 0, 0);
        a2 = __builtin_amdgcn_mfma_f32_16x16x32_bf16(af, b2, a2, 0, 0, 0);
        a3 = __builtin_amdgcn_mfma_f32_16x16x32_bf16(af, b3, a3, 0, 0, 0);
        __syncthreads();
    }
    // direct B-panel write
    const int jt = (i0 >> 5) + (w >> 1);
    const int kg = ((w & 1) << 1) + (grp >> 1);
    const int lanep = kg * 16 + r16;
    const int ebase = (grp & 1) * 4;
    unsigned short* bp = Bp1 + ((size_t)(h * 128 + jt)) * 2048 + lanep * 8 + ebase;
    {
        uint2 v;
        v.x = pack2(a0[0], a0[1]); v.y = pack2(a0[2], a0[3]); *(uint2*)(bp + 0 * 512) = v;
        v.x = pack2(a1[0], a1[1]); v.y = pack2(a1[2], a1[3]); *(uint2*)(bp + 1 * 512) = v;
        v.x = pack2(a2[0], a2[1]); v.y = pack2(a2[2], a2[3]); *(uint2*)(bp + 2 * 512) = v;
        v.x = pack2(a3[0], a3[1]); v.y = pack2(a3[2], a3[3]); *(uint2*)(bp + 3 * 512) = v;
    }
    const float* ap = a_s + h * 128;
    float a1v[4], a2v[4];
#pragma unroll
    for (int n = 0; n < 4; ++n) { a1v[n] = ap[r16 + 16 * n]; a2v[n] = ap[64 + r16 + 16 * n]; }
    float wmax = -3.0e38f;
#pragma unroll
    for (int r = 0; r < 4; ++r) {
        const int orow = i0 + w * 16 + grp * 4 + r;
        float s1 = a0[r] * a1v[0] + a1[r] * a1v[1] + a2[r] * a1v[2] + a3[r] * a1v[3];
        float s2 = a0[r] * a2v[0] + a1[r] * a2v[1] + a2[r] * a2v[2] + a3[r] * a2v[3];
#pragma unroll
        for (int o2 = 1; o2 < 16; o2 <<= 1) { s1 += __shfl_xor(s1, o2); s2 += __shfl_xor(s2, o2); }
        s1 *= LOG2E; s2 *= LOG2E;
        if (r16 == 0) { f1L[h * NN + orow] = s1; f2L[h * NN + orow] = s2; }
        wmax = fmaxf(wmax, s2);
    }
    wmax = fmaxf(wmax, __shfl_xor(wmax, 16));
    wmax = fmaxf(wmax, __shfl_xor(wmax, 32));
    if (lane == 0) atomicMax(&FM1u[h], fenc(wmax));
}

// ---------------- GEMM2: Bp2 = pack(x2 @ W_out), f12/f22 + FM2 ----------------
__global__ __launch_bounds__(256) void gemm2_k(const unsigned short* __restrict__ x2b,
                                               const unsigned short* __restrict__ WoT,
                                               const float* __restrict__ a_out,
                                               unsigned short* __restrict__ Bp2,
                                               float* __restrict__ f12L,
                                               float* __restrict__ f22L,
                                               unsigned* __restrict__ FM2u) {
    __shared__ unsigned short xs[64 * 40];
    __shared__ unsigned short wsm[48 * 40];
    const int tid = threadIdx.x;
    const int w = tid >> 6, lane = tid & 63, r16 = lane & 15, grp = lane >> 4;
    const int i0 = blockIdx.x << 6;
    const int srow = tid >> 2, sseg = tid & 3;
    const unsigned short* xsrc = x2b + (size_t)(i0 + srow) * NF + sseg * 8;
    const unsigned short* wsrc = WoT + (size_t)srow * NF + sseg * 8;
    f32x4 a0 = {0,0,0,0}, a1 = {0,0,0,0}, a2 = {0,0,0,0};
    bh8 rx = *(const bh8*)(xsrc);
    bh8 rw; if (tid < 192) rw = *(const bh8*)(wsrc);
    for (int kb = 0; kb < NF; kb += 32) {
        *(bh8*)(xs + srow * 40 + sseg * 8) = rx;
        if (tid < 192) *(bh8*)(wsm + srow * 40 + sseg * 8) = rw;
        __syncthreads();
        if (kb + 32 < NF) {
            rx = *(const bh8*)(xsrc + kb + 32);
            if (tid < 192) rw = *(const bh8*)(wsrc + kb + 32);
        }
        bh8 af = *(const bh8*)(xs + (w * 16 + r16) * 40 + grp * 8);
        bh8 b0 = *(const bh8*)(wsm + (r16) * 40 + grp * 8);
        bh8 b1 = *(const bh8*)(wsm + (16 + r16) * 40 + grp * 8);
        bh8 b2 = *(const bh8*)(wsm + (32 + r16) * 40 + grp * 8);
        a0 = __builtin_amdgcn_mfma_f32_16x16x32_bf16(af, b0, a0, 0, 0, 0);
        a1 = __builtin_amdgcn_mfma_f32_16x16x32_bf16(af, b1, a1, 0, 0, 0);
        a2 = __builtin_amdgcn_mfma_f32_16x16x32_bf16(af, b2, a2, 0, 0, 0);
        __syncthreads();
    }
    const int jt = (i0 >> 5) + (w >> 1);
    const int kg = ((w & 1) << 1) + (grp >> 1);
    const int lanep = kg * 16 + r16;
    const int ebase = (grp & 1) * 4;
    unsigned short* bp = Bp2 + (size_t)jt * 1536 + lanep * 8 + ebase;
    {
        uint2 v;
        v.x = pack2(a0[0], a0[1]); v.y = pack2(a0[2], a0[3]); *(uint2*)(bp + 0 * 512) = v;
        v.x = pack2(a1[0], a1[1]); v.y = pack2(a1[2], a1[3]); *(uint2*)(bp + 1 * 512) = v;
        v.x = pack2(a2[0], a2[1]); v.y = pack2(a2[2], a2[3]); *(uint2*)(bp + 2 * 512) = v;
    }
    float a1v[3], a2v[3];
#pragma unroll
    for (int n = 0; n < 3; ++n) {
        int col = r16 + 16 * n;
        a1v[n] = col < NCLS ? a_out[col] : 0.f;
        a2v[n] = col < NCLS ? a_out[NCLS + col] : 0.f;
    }
    float wmax = -3.0e38f;
#pragma unroll
    for (int r = 0; r < 4; ++r) {
        const int orow = i0 + w * 16 + grp * 4 + r;
        float s1 = a0[r] * a1v[0] + a1[r] * a1v[1] + a2[r] * a1v[2];
        float s2 = a0[r] * a2v[0] + a1[r] * a2v[1] + a2[r] * a2v[2];
#pragma unroll
        for (int o2 = 1; o2 < 16; o2 <<= 1) { s1 += __shfl_xor(s1, o2); s2 += __shfl_xor(s2, o2); }
        s1 *= LOG2E; s2 *= LOG2E;
        if (r16 == 0) { f12L[orow] = s1; f22L[orow] = s2; }
        wmax = fmaxf(wmax, s2);
    }
    wmax = fmaxf(wmax, __shfl_xor(wmax, 16));
    wmax = fmaxf(wmax, __shfl_xor(wmax, 32));
    if (lane == 0) atomicMax(&FM2u[0], fenc(wmax));
}

// ---------------- attn layer 1: EF tables + adj in LDS, factored scores (round-5 form) ----------------
__global__ __launch_bounds__(512, 4) void attn1_k(const unsigned short* __restrict__ Bp1,
                                                  const unsigned char* __restrict__ adjp,
                                                  const float* __restrict__ f1L,
                                                  const float* __restrict__ f2L,
                                                  const unsigned* __restrict__ FM1u,
                                                  unsigned short* __restrict__ x2b) {
    __shared__ float EFs[8192];                 // 32 KiB: (E,F) pairs for 4096 j (reused as comb)
    __shared__ unsigned ADJd[64 * 4 * 33];      // 33.8 KiB: adj dwords, 33-dword pitch
    const int tid = threadIdx.x, w = tid >> 6, lane = tid & 63;
    const int r16 = lane & 15, grp = lane >> 4;
    const int rowg = w & 3, jq = w >> 2;
    const int h = blockIdx.y;
    const int i0 = blockIdx.x * 64;
    const float fm = fdec(FM1u[h]);
    const float* f2p = f2L + h * NN;
    // stage EF (each thread 8 j's)
    for (int t = 0; t < 8; ++t) {
        int j = tid + t * 512;
        float d = f2p[j] - fm;
        EFs[2 * j] = exp2fast(d);
        EFs[2 * j + 1] = exp2fast(0.2f * d);
    }
    // stage adjacency rows [i0, i0+64) with 33-dword pitch
    {
        const unsigned* asrc = (const unsigned*)(adjp + (size_t)i0 * 512);
        for (int t = 0; t < 16; ++t) {
            int idx = tid + t * 512;
            ADJd[(idx >> 5) * 33 + (idx & 31)] = asrc[idx];
        }
    }
    const int irow = i0 + rowg * 16 + r16;
    const float f1v = f1L[h * NN + irow];
    const float mL = lrelu(f1v + fm);
    const float A = exp2fast(f1v + fm - mL);
    const float B = exp2fast(__builtin_fmaf(0.2f, f1v + fm, -mL));
    __syncthreads();
    const unsigned* adjrd = ADJd + ((rowg * 16 + r16) * 4 + grp) * 33 + jq * 16;
    const float* efp = EFs + grp * 16;
    const unsigned short* Bbase = Bp1 + (size_t)h * 128 * 2048 + lane * 8;
    f32x4 acc0 = {0,0,0,0}, acc1 = {0,0,0,0}, acc2 = {0,0,0,0}, acc3 = {0,0,0,0}, accd = {0,0,0,0};
    const short ov = (r16 == 0) ? (short)0x3F80 : (short)0;
    bh8 ones;
#pragma unroll
    for (int e = 0; e < 8; ++e) ones[e] = ov;
    bh8 nb0, nb1, nb2, nb3;
#define PREF1(JT) { const unsigned short* Bn = Bbase + (size_t)(JT) * 2048;              \
        nb0 = *(const bh8*)(Bn);        nb1 = *(const bh8*)(Bn + 512);                    \
        nb2 = *(const bh8*)(Bn + 1024); nb3 = *(const bh8*)(Bn + 1536); }
    const int jtbase = jq * 64;
    PREF1(jtbase);
    for (int jt4 = 0; jt4 < 16; ++jt4) {
        const unsigned mdw = adjrd[jt4];
#pragma unroll
        for (int u = 0; u < 4; ++u) {
            const int jt = jtbase + jt4 * 4 + u;
            bh8 b0 = nb0, b1 = nb1, b2 = nb2, b3 = nb3;
            PREF1(jt + 1);
            const float* e4 = efp + jt * 64;
            float4 ea = *(const float4*)(e4);
            float4 eb = *(const float4*)(e4 + 4);
            float4 ec = *(const float4*)(e4 + 8);
            float4 ed = *(const float4*)(e4 + 12);
            const int bb = u * 8;
            union { bh8 v; unsigned u32[4]; } pk;
            {
                float p0 = bmask(fmaxf(A * ea.x, B * ea.y), mdw, bb + 0);
                float p1 = bmask(fmaxf(A * ea.z, B * ea.w), mdw, bb + 1);
                pk.u32[0] = __builtin_amdgcn_perm(__builtin_bit_cast(unsigned, p1),
                                                  __builtin_bit_cast(unsigned, p0), 0x07060302u);
                float p2 = bmask(fmaxf(A * eb.x, B * eb.y), mdw, bb + 2);
                float p3 = bmask(fmaxf(A * eb.z, B * eb.w), mdw, bb + 3);
                pk.u32[1] = __builtin_amdgcn_perm(__builtin_bit_cast(unsigned, p3),
                                                  __builtin_bit_cast(unsigned, p2), 0x07060302u);
                float p4 = bmask(fmaxf(A * ec.x, B * ec.y), mdw, bb + 4);
                float p5 = bmask(fmaxf(A * ec.z, B * ec.w), mdw, bb + 5);
                pk.u32[2] = __builtin_amdgcn_perm(__builtin_bit_cast(unsigned, p5),
                                                  __builtin_bit_cast(unsigned, p4), 0x07060302u);
                float p6 = bmask(fmaxf(A * ed.x, B * ed.y), mdw, bb + 6);
                float p7 = bmask(fmaxf(A * ed.z, B * ed.w), mdw, bb + 7);
                pk.u32[3] = __builtin_amdgcn_perm(__builtin_bit_cast(unsigned, p7),
                                                  __builtin_bit_cast(unsigned, p6), 0x07060302u);
            }
            acc0 = __builtin_amdgcn_mfma_f32_16x16x32_bf16(pk.v, b0, acc0, 0, 0, 0);
            acc1 = __builtin_amdgcn_mfma_f32_16x16x32_bf16(pk.v, b1, acc1, 0, 0, 0);
            acc2 = __builtin_amdgcn_mfma_f32_16x16x32_bf16(pk.v, b2, acc2, 0, 0, 0);
            acc3 = __builtin_amdgcn_mfma_f32_16x16x32_bf16(pk.v, b3, acc3, 0, 0, 0);
            accd = __builtin_amdgcn_mfma_f32_16x16x32_bf16(pk.v, ones, accd, 0, 0, 0);
        }
    }
#undef PREF1
    __syncthreads();                 // everyone done reading EFs/ADJd
    float (*comb)[64][21] = (float(*)[64][21])EFs;   // 21-pad: conflict-free (5376 floats < 8192)
    if (jq == 1) {
        float* cb = &comb[rowg][lane][0];
#pragma unroll
        for (int r = 0; r < 4; ++r) {
            cb[r] = acc0[r]; cb[4 + r] = acc1[r]; cb[8 + r] = acc2[r];
            cb[12 + r] = acc3[r]; cb[16 + r] = accd[r];
        }
    }
    __syncthreads();
    if (jq == 0) {
        const float* cb = &comb[rowg][lane][0];
#pragma unroll
        for (int r = 0; r < 4; ++r) {
            acc0[r] += cb[r]; acc1[r] += cb[4 + r]; acc2[r] += cb[8 + r];
            acc3[r] += cb[12 + r]; accd[r] += cb[16 + r];
        }
#pragma unroll
        for (int r = 0; r < 4; ++r) {
            const float den = __shfl(accd[r], lane & 48);
            const float inv = 1.0f / den;
            unsigned short* o = x2b + (size_t)(i0 + rowg * 16 + grp * 4 + r) * NF + h * 64 + r16;
            o[0]  = f2bu(elu1(acc0[r] * inv));
            o[16] = f2bu(elu1(acc1[r] * inv));
            o[32] = f2bu(elu1(acc2[r] * inv));
            o[48] = f2bu(elu1(acc3[r] * inv));
        }
    }
}

// ---------------- attn layer 2: single pass, fused elu + log_softmax ----------------
// block = 16 rows x all 4096 j; 8 waves split j 8-way; LDS tree combine
__global__ __launch_bounds__(512, 6) void attn2_k(const unsigned short* __restrict__ Bp2,
                                                  const unsigned char* __restrict__ adjp,
                                                  const float* __restrict__ f12L,
                                                  const float* __restrict__ f22L,
                                                  const unsigned* __restrict__ FM2u,
                                                  float* __restrict__ out) {
    __shared__ float EFs[8192];          // 32 KiB
    __shared__ float comb[8][64][17];    // 34.8 KiB
    const int tid = threadIdx.x, w = tid >> 6, lane = tid & 63;
    const int r16 = lane & 15, grp = lane >> 4;
    const int i0 = blockIdx.x * 16;
    const int i = i0 + r16;
    const float fm = fdec(FM2u[0]);
    for (int t = 0; t < 8; ++t) {
        int j = tid + t * 512;
        float d = f22L[j] - fm;
        EFs[2 * j] = exp2fast(d);
        EFs[2 * j + 1] = exp2fast(0.2f * d);
    }
    const float f1v = f12L[i];
    const float mL = lrelu(f1v + fm);
    const float A = exp2fast(f1v + fm - mL);
    const float B = exp2fast(__builtin_fmaf(0.2f, f1v + fm, -mL));
    __syncthreads();
    const int jt0 = w * 16;
    const uint4 a4 = *(const uint4*)(adjp + ((size_t)i * 4 + grp) * 128 + jt0);
    f32x4 acc0 = {0,0,0,0}, acc1 = {0,0,0,0}, acc2 = {0,0,0,0}, accd = {0,0,0,0};
    const short ov = (r16 == 0) ? (short)0x3F80 : (short)0;
    bh8 ones;
#pragma unroll
    for (int e = 0; e < 8; ++e) ones[e] = ov;
    const unsigned short* Bbase = Bp2 + lane * 8;
    const float* efp = EFs + grp * 16;
    bh8 nb0, nb1, nb2;
#define PREF2(JT) { const unsigned short* Bn = Bbase + (size_t)(JT) * 1536;              \
        nb0 = *(const bh8*)(Bn); nb1 = *(const bh8*)(Bn + 512); nb2 = *(const bh8*)(Bn + 1024); }
    PREF2(jt0);
#pragma unroll
    for (int q = 0; q < 4; ++q) {
        const unsigned mdw = (q == 0) ? a4.x : (q == 1) ? a4.y : (q == 2) ? a4.z : a4.w;
#pragma unroll
        for (int u = 0; u < 4; ++u) {
            const int jt = jt0 + q * 4 + u;
            bh8 b0 = nb0, b1 = nb1, b2 = nb2;
            PREF2(jt + 1);
            const float* e4 = efp + jt * 64;
            float4 ea = *(const float4*)(e4);
            float4 eb = *(const float4*)(e4 + 4);
            float4 ec = *(const float4*)(e4 + 8);
            float4 ed = *(const float4*)(e4 + 12);
            const int bb = u * 8;
            union { bh8 v; unsigned u32[4]; } pk;
            {
                float p0 = bmask(fmaxf(A * ea.x, B * ea.y), mdw, bb + 0);
                float p1 = bmask(fmaxf(A * ea.z, B * ea.w), mdw, bb + 1);
                pk.u32[0] = __builtin_amdgcn_perm(__builtin_bit_cast(unsigned, p1),
                                                  __builtin_bit_cast(unsigned, p0), 0x07060302u);
                float p2 = bmask(fmaxf(A * eb.x, B * eb.y), mdw, bb + 2);
                float p3 = bmask(fmaxf(A * eb.z, B * eb.w), mdw, bb + 3);
                pk.u32[1] = __builtin_amdgcn_perm(__builtin_bit_cast(unsigned, p3),
                                                  __builtin_bit_cast(unsigned, p2), 0x07060302u);
                float p4 = bmask(fmaxf(A * ec.x, B * ec.y), mdw, bb + 4);
                float p5 = bmask(fmaxf(A * ec.z, B * ec.w), mdw, bb + 5);
                pk.u32[2] = __builtin_amdgcn_perm(__builtin_bit_cast(unsigned, p5),
                                                  __builtin_bit_cast(unsigned, p4), 0x07060302u);
                float p6 = bmask(fmaxf(A * ed.x, B * ed.y), mdw, bb + 6);
                float p7 = bmask(fmaxf(A * ed.z, B * ed.w), mdw, bb + 7);
                pk.u32[3] = __builtin_amdgcn_perm(__builtin_bit_cast(unsigned, p7),
                                                  __builtin_bit_cast(unsigned, p6), 0x07060302u);
            }
            acc0 = __builtin_amdgcn_mfma_f32_16x16x32_bf16(pk.v, b0, acc0, 0, 0, 0);
            acc1 = __builtin_amdgcn_mfma_f32_16x16x32_bf16(pk.v, b1, acc1, 0, 0, 0);
            acc2 = __builtin_amdgcn_mfma_f32_16x16x32_bf16(pk.v, b2, acc2, 0, 0, 0);
            accd = __builtin_amdgcn_mfma_f32_16x16x32_bf16(pk.v, ones, accd, 0, 0, 0);
        }
    }
#undef PREF2
    // tree combine over 8 waves
    {
        float* cb = &comb[w][lane][0];
#pragma unroll
        for (int r = 0; r < 4; ++r) {
            cb[r] = acc0[r]; cb[4 + r] = acc1[r]; cb[8 + r] = acc2[r]; cb[12 + r] = accd[r];
        }
    }
    __syncthreads();
    if (w < 4) {
        const float* sb = &comb[w + 4][lane][0];
        float* cb = &comb[w][lane][0];
#pragma unroll
        for (int r = 0; r < 4; ++r) {
            acc0[r] += sb[r]; acc1[r] += sb[4 + r]; acc2[r] += sb[8 + r]; accd[r] += sb[12 + r];
            cb[r] = acc0[r]; cb[4 + r] = acc1[r]; cb[8 + r] = acc2[r]; cb[12 + r] = accd[r];
        }
    }
    __syncthreads();
    if (w < 2) {
        const float* sb = &comb[w + 2][lane][0];
        float* cb = &comb[w][lane][0];
#pragma unroll
        for (int r = 0; r < 4; ++r) {
            acc0[r] += sb[r]; acc1[r] += sb[4 + r]; acc2[r] += sb[8 + r]; accd[r] += sb[12 + r];
            cb[r] = acc0[r]; cb[4 + r] = acc1[r]; cb[8 + r] = acc2[r]; cb[12 + r] = accd[r];
        }
    }
    __syncthreads();
    if (w == 0) {
        const float* sb = &comb[1][lane][0];
#pragma unroll
        for (int r = 0; r < 4; ++r) {
            acc0[r] += sb[r]; acc1[r] += sb[4 + r]; acc2[r] += sb[8 + r]; accd[r] += sb[12 + r];
        }
        // finish: denom, elu, log_softmax, write
#pragma unroll
        for (int r = 0; r < 4; ++r) {
            const int row = grp * 4 + r;
            const float den = __shfl(accd[r], lane & 48);
            const float inv = 1.0f / den;
            float v0 = elu1(acc0[r] * inv);
            float v1 = elu1(acc1[r] * inv);
            float v2 = (r16 < 8) ? elu1(acc2[r] * inv) : -3.0e38f;
            float mx = fmaxf(fmaxf(v0, v1), v2);
#pragma unroll
            for (int o = 1; o < 16; o <<= 1) mx = fmaxf(mx, __shfl_xor(mx, o));
            float ex = __expf(v0 - mx) + __expf(v1 - mx) + ((r16 < 8) ? __expf(v2 - mx) : 0.f);
#pragma unroll
            for (int o = 1; o < 16; o <<= 1) ex += __shfl_xor(ex, o);
            const float lse = mx + logf(ex);
            float* op = out + (size_t)(i0 + row) * NCLS;
            op[r16] = v0 - lse;
            op[16 + r16] = v1 - lse;
            if (r16 < 8) op[32 + r16] = v2 - lse;
        }
    }
}

// ---------------- workspace layout (bytes) ----------------
#define OFF_XB   0ULL           // 4096*512*2 = 4194304
#define OFF_WT   4194304ULL     // 512*512*2  = 524288
#define OFF_WOT  4718592ULL     // 48*512*2   = 49152
#define OFF_BP1  4767744ULL     // 8*128*2048*2 = 4194304
#define OFF_X2B  8962048ULL     // 4096*512*2 = 4194304
#define OFF_BP2  13156352ULL    // 128*1536*2 = 393216
#define OFF_F1L  13549568ULL    // 8*4096*4 = 131072
#define OFF_F2L  13680640ULL    // 131072
#define OFF_F12  13811712ULL    // 16384
#define OFF_F22  13828096ULL    // 16384
#define OFF_FM1  13844480ULL    // 256
#define OFF_FM2  13844736ULL    // 256
#define OFF_ADJ  13844992ULL    // 4096*4*128 = 2097152 -> end 15942144

extern "C" void kernel_launch(void* const* d_in, const int* in_sizes, int n_in,
                              void* d_out, int out_size, void* d_ws, size_t ws_size,
                              hipStream_t stream) {
    const float* x     = (const float*)d_in[0];
    const float* adj   = (const float*)d_in[1];
    const float* Ws    = (const float*)d_in[2];
    const float* a_s   = (const float*)d_in[3];
    const float* W_out = (const float*)d_in[4];
    const float* a_out = (const float*)d_in[5];
    float* out = (float*)d_out;
    char* w = (char*)d_ws;

    unsigned short* xb  = (unsigned short*)(w + OFF_XB);
    unsigned short* WT  = (unsigned short*)(w + OFF_WT);
    unsigned short* WoT = (unsigned short*)(w + OFF_WOT);
    unsigned short* Bp1 = (unsigned short*)(w + OFF_BP1);
    unsigned short* x2b = (unsigned short*)(w + OFF_X2B);
    unsigned short* Bp2 = (unsigned short*)(w + OFF_BP2);
    float* f1L = (float*)(w + OFF_F1L);
    float* f2L = (float*)(w + OFF_F2L);
    float* f12 = (float*)(w + OFF_F12);
    float* f22 = (float*)(w + OFF_F22);
    unsigned* FM1u = (unsigned*)(w + OFF_FM1);
    unsigned* FM2u = (unsigned*)(w + OFF_FM2);
    unsigned char* adjp = (unsigned char*)(w + OFF_ADJ);

    prep_all_k<<<11360, 256, 0, stream>>>(x, adj, Ws, W_out, xb, WT, WoT, adjp, FM1u, FM2u);
    gemm1_k<<<dim3(32, 8), 512, 0, stream>>>(xb, WT, a_s, Bp1, f1L, f2L, FM1u);
    attn1_k<<<dim3(64, 8), 512, 0, stream>>>(Bp1, adjp, f1L, f2L, FM1u, x2b);
    gemm2_k<<<64, 256, 0, stream>>>(x2b, WoT, a_out, Bp2, f12, f22, FM2u);
    attn2_k<<<256, 512, 0, stream>>>(Bp2, adjp, f12, f22, FM2u, out);
}